// Round 8
// baseline (194.765 us; speedup 1.0000x reference)
//
#include <hip/hip_runtime.h>

// PatchesCreate: images [B=64, H=384, W=384, C=3] f32 (NHWC) ->
// patches [B, 576, 768] f32, P=16, G=24.
//
// v9 = v7 geometry, PLAIN loads + TRUE-BYPASS stores (asm sc0 sc1 nt).
//
// Why: all NT/NT schedules plateau at 57.5+-1 us dispatch (~3.9 TB/s).
// Key anomaly: v5 (plain loads + builtin-NT stores) had FETCH_SIZE
// = 55,332 KB, IDENTICAL to v4 (plain stores) -> the builtin nt store did
// NOT keep the output stream out of the Infinity Cache; output still evicted
// half the 113 MB input (in+out = 226 MB vs 256 MB L3). So "plain loads are
// slower" was measured with a polluted L3. Untested corner of the flag
// matrix: plain loads (input allocates + stays L3-resident across repeated
// dispatches) + maximal-bypass stores `sc0 sc1 nt` (output never touches
// L3). Expected: FETCH collapses (<25 MB), reads served from L3, writes
// stream at the fill-proven 6.7 TB/s -> dispatch toward 42-50 us.
// Falsification branches (committed): FETCH drops but time flat -> L3 reads
// not faster -> roofline; FETCH stays 55 MB -> fill-eviction -> roofline.
//
// Geometry (v7-identical): one half-row-pair tile per wave (rows 2p,2p+1,
// gx in [12h,12h+12)): 2 contiguous 2304 B input runs, 12 aligned 384 B
// output runs, wave-private 4.6 KB LDS, 18.5 KB/block, 8 blocks/CU
// (32 waves/CU), one-shot 6144 blocks, no barriers.

typedef float f2 __attribute__((ext_vector_type(2)));

constexpr int ROW2   = 576;               // f2 per image row
constexpr int IMG2   = 384 * ROW2;        // 221184 f2 per image (in == out)
constexpr int GY2    = 24 * 384;          // 9216 f2 per gy-slab of patches
constexpr int LSTR2  = 289;               // 288 + 1 f2 pad
constexpr int LWAVE2 = 2 * LSTR2;         // 578 f2 = 4624 B per wave
constexpr int BLOCK  = 256;
constexpr int NTILE  = 64 * 24 * 8 * 2;   // 24576 half-row-pair tiles
constexpr int GRIDN  = NTILE / 4;         // 6144 blocks, one tile per wave

__global__ __launch_bounds__(BLOCK, 8)
void patches_kernel(const f2* __restrict__ in, f2* __restrict__ out) {
    __shared__ f2 lds[4 * LWAVE2];        // 18,496 B -> 8 blocks/CU
    const int wv = threadIdx.x >> 6;
    const int l  = threadIdx.x & 63;
    f2* __restrict__ L = &lds[wv * LWAVE2];

    const int tau = blockIdx.x * 4 + wv;  // tile id
    const int h   = tau & 1;              // gx half: 0 or 1
    const int t1  = tau >> 1;
    const int p   = t1 & 7;               // row-pair within slab
    const int t2  = t1 >> 3;
    const int gy  = t2 % 24;
    const int b   = t2 / 24;

    // ---- load: PLAIN (allocate; input stays L3-resident across dispatches)
    const f2* ibase = in + b * IMG2 + (gy * 16 + 2 * p) * ROW2 + h * 288;
    f2 v[9];
#pragma unroll
    for (int j = 0; j < 9; ++j) {
        int i  = l + j * 64;              // 0..575
        int r  = (i >= 288) ? 1 : 0;      // local row
        int c2 = i - r * 288;             // 0..287
        v[j] = ibase[r * ROW2 + c2];
    }

    // ---- stage in wave-private LDS (compiler waits precisely on v's loads)
#pragma unroll
    for (int j = 0; j < 9; ++j) {
        int i  = l + j * 64;
        int r  = (i >= 288) ? 1 : 0;
        int c2 = i - r * 288;
        L[r * LSTR2 + c2] = v[j];
    }
    asm volatile("s_waitcnt lgkmcnt(0)" ::: "memory");
    __builtin_amdgcn_sched_barrier(0);

    // ---- gather in output order; TRUE-BYPASS stores (sc0 sc1 nt):
    //      output stream never allocates in L2/L3, writes stream to HBM.
    f2* obase = out + b * IMG2 + gy * GY2 + h * (12 * 384) + p * 48;
#pragma unroll
    for (int j = 0; j < 9; ++j) {
        int o   = l + j * 64;             // 0..575
        int gxl = o / 48;                 // 0..11
        int w   = o - gxl * 48;           // 0..47
        int py2 = (w >= 24) ? 1 : 0;
        int w2  = w - py2 * 24;           // 0..23
        f2 x = L[py2 * LSTR2 + gxl * 24 + w2];
        f2* a = obase + gxl * 384 + py2 * 24 + w2;
        asm volatile("global_store_dwordx2 %0, %1, off sc0 sc1 nt"
                     :: "v"(a), "v"(x) : "memory");
    }
}

extern "C" void kernel_launch(void* const* d_in, const int* in_sizes, int n_in,
                              void* d_out, int out_size, void* d_ws, size_t ws_size,
                              hipStream_t stream) {
    const f2* in  = (const f2*)d_in[0];
    f2*       out = (f2*)d_out;
    patches_kernel<<<GRIDN, BLOCK, 0, stream>>>(in, out);
}

// Round 9
// 188.013 us; speedup vs baseline: 1.0359x; 1.0359x over previous
//
#include <hip/hip_runtime.h>

// PatchesCreate: images [B=64, H=384, W=384, C=3] f32 (NHWC) ->
// patches [B, 576, 768] f32, P=16, G=24.
//
// v10 = v6 (barrier-free wave-private row-pair pipeline) with the LAST
// untested cache-policy cell: NT LOADS + PLAIN STORES.
//
// Matrix so far (dispatch us): NT/NT=56.8-58, plain/plain=68.5,
// plain/NT=67.3, plain/bypass=67.0, bypass/NT=57.6. NT-load/plain-store is
// the only hole, with a real mechanism: NT loads keep the input OUT of L3
// entirely, so the full 256 MB L3 belongs to the 110 MB output stream ->
// plain stores absorb in cache and write back as controller-batched long
// bursts, avoiding the fine-grained NT-read/NT-write interleave at the HBM
// channels (bus turnaround) that plausibly caps NT/NT at 3.9 TB/s while
// write-only fills run 6.7 and cache-buffered copy runs 6.3.
// Round-4's "NT stores neutral" was measured under PLAIN loads (polluted
// L3) and does not cover this cell.
//
// Structure (v6-identical): persistent 1024 WGs x 4 waves, one row-pair
// (2 rows x 288 f4 = 9 KiB) per wave-tile, wave-private 9.25 KiB LDS, no
// barriers, depth-1 register prefetch, 3 tiles/wave.
// If this is null -> revert to v3 and declare roofline.

typedef float f4 __attribute__((ext_vector_type(4)));

constexpr int ROW4  = 288;                // f4 per image row
constexpr int IMG4  = 384 * ROW4;         // 110592 f4 per image (in == out)
constexpr int GY4   = 24 * 192;           // 4608 f4 per gy-slab of patches
constexpr int LROW  = ROW4 + 1;           // 289: +16 B pad per LDS row
constexpr int LWAVE = 2 * LROW;           // 578 f4 per wave region
constexpr int BLOCK = 256;                // 4 waves
constexpr int GRID  = 1024;               // persistent; 4 WGs/CU
constexpr int NW    = GRID * 4;           // 4096 waves
constexpr int NTILE = 64 * 24 * 8;        // 12288 row-pair tiles
constexpr int NITER = NTILE / NW;         // 3 tiles per wave
constexpr int PT    = 9;                  // f4 per lane per tile (576/64)

__device__ __forceinline__ int in_base_of(int tau) {
    int p = tau & 7, t2 = tau >> 3;
    int gy = t2 % 24, b = t2 / 24;
    return b * IMG4 + (gy * 16 + 2 * p) * ROW4;
}
__device__ __forceinline__ int out_base_of(int tau) {
    int p = tau & 7, t2 = tau >> 3;
    int gy = t2 % 24, b = t2 / 24;
    return b * IMG4 + gy * GY4 + p * 24;
}

__global__ __launch_bounds__(BLOCK, 4)
void patches_kernel(const f4* __restrict__ in, f4* __restrict__ out) {
    __shared__ f4 lds[4 * LWAVE];         // 36,992 B -> 4 WGs/CU
    const int wv = threadIdx.x >> 6;
    const int l  = threadIdx.x & 63;
    f4* __restrict__ L = &lds[wv * LWAVE];
    const int W = blockIdx.x * 4 + wv;    // global wave id

    f4 v[PT], u[PT];
    {
        const f4* p = in + in_base_of(W) + l;
#pragma unroll
        for (int j = 0; j < PT; ++j)
            v[j] = __builtin_nontemporal_load(p + j * 64);
    }

#pragma unroll
    for (int i = 0; i < NITER; ++i) {
        // ---- prefetch tile i+1 (stays in flight through this tile's work)
        if (i + 1 < NITER) {
            const f4* p = in + in_base_of(W + (i + 1) * NW) + l;
#pragma unroll
            for (int j = 0; j < PT; ++j)
                u[j] = __builtin_nontemporal_load(p + j * 64);
            __builtin_amdgcn_sched_barrier(0);   // pin issue point
        }

        // ---- ds_write own tile (compiler waits precisely on v's loads)
#pragma unroll
        for (int j = 0; j < PT; ++j) {
            int idx = l + j * 64;                // 0..575
            int r   = idx / ROW4;                // 0 or 1
            int c   = idx - r * ROW4;            // 0..287
            L[r * LROW + c] = v[j];
        }
        asm volatile("s_waitcnt lgkmcnt(0)" ::: "memory");
        __builtin_amdgcn_sched_barrier(0);       // no read hoisted above wait

        // ---- gather in output order; PLAIN stores: output absorbs in the
        //      (input-free) L3 and writes back in batched bursts
        const int ob = out_base_of(W + i * NW);
#pragma unroll
        for (int j = 0; j < PT; ++j) {
            int o   = l + j * 64;                // 0..575
            int gx  = o / 24;                    // 0..23
            int w2  = o - gx * 24;               // py2*12 + k
            int py2 = w2 / 12;
            int k   = w2 - py2 * 12;
            out[ob + gx * 192 + w2] = L[py2 * LROW + gx * 12 + k];
        }

        if (i + 1 < NITER) {
#pragma unroll
            for (int j = 0; j < PT; ++j) v[j] = u[j];
        }
    }
}

extern "C" void kernel_launch(void* const* d_in, const int* in_sizes, int n_in,
                              void* d_out, int out_size, void* d_ws, size_t ws_size,
                              hipStream_t stream) {
    const f4* in  = (const f4*)d_in[0];
    f4*       out = (f4*)d_out;
    patches_kernel<<<GRID, BLOCK, 0, stream>>>(in, out);
}

// Round 10
// 186.126 us; speedup vs baseline: 1.0464x; 1.0101x over previous
//
#include <hip/hip_runtime.h>

// PatchesCreate: images [B=64, H=384, W=384, C=3] f32 (NHWC) ->
// patches [B, 576, 768] f32, P=16, G=24.
//
// FINAL (v11 = v3, best measured: 184.78 us bench / ~56.8 us dispatch).
//
// Session conclusion: this kernel is at the harness-context roofline.
//  - Cache-policy matrix complete: NT/NT best (plain loads +10 us).
//  - Six schedule structures within +-1 us; occupancy 27%->65% no effect.
//  - Control: the runtime's own copyBuffer (pure 113 MB D2D memcpy, same
//    buffers, same harness) runs 69 us -- ~18% SLOWER than this kernel.
//  - Bench dur_us carries ~128 us of fixed in-window harness fill overhead.
//
// Structure: persistent, 1024 WGs (4/CU, LDS 36,992 B), 3 half-slab tiles
// per WG, register prefetch of tile i+1 before tile i's barriers, raw
// s_barrier + manual lgkmcnt(0) so prefetch loads and NT stores stay in
// flight across barriers. Both global streams long-sequential; NT on both
// sides (measured best cache policy).

typedef float f4 __attribute__((ext_vector_type(4)));

constexpr int C     = 3;
constexpr int P     = 16;
constexpr int G     = 24;                 // 384/16
constexpr int ROW4  = 384 * C / 4;        // 288 float4 per image row
constexpr int IMG4  = 384 * ROW4;         // 110592 float4 per image (in == out)
constexpr int HR    = 8;                  // image rows staged per tile
constexpr int TILE4 = HR * ROW4;          // 2304 float4 = 36 KiB
constexpr int LSTR  = ROW4 + 1;           // 289: +16 B pad per LDS row
constexpr int BLOCK = 256;
constexpr int PT    = TILE4 / BLOCK;      // 9 float4 per thread (exact)
constexpr int NSLAB = 64 * G * 2;         // 3072 half-slabs
constexpr int GRID  = 1024;               // 4 WGs/CU resident, persistent
constexpr int NITER = NSLAB / GRID;       // 3 tiles per WG

constexpr int GY4   = G * P * P * C / 4;  // 4608 f4 per gy-group of patches
constexpr int HALF4 = HR * P * C / 4;     // 96 f4: half-patch offset

__device__ __forceinline__ int in_base_of(int s) {
    int half = s & 1, bg = s >> 1;
    int gy = bg % G, b = bg / G;
    return b * IMG4 + (gy * P + half * HR) * ROW4;
}
__device__ __forceinline__ int out_base_of(int s) {
    int half = s & 1, bg = s >> 1;
    int gy = bg % G, b = bg / G;
    return b * IMG4 + gy * GY4 + half * HALF4;
}

__global__ __launch_bounds__(BLOCK, 4)
void patches_kernel(const f4* __restrict__ in, f4* __restrict__ out) {
    __shared__ f4 lds[HR * LSTR];         // 36,992 B -> 4 WGs/CU
    const int t  = threadIdx.x;
    const int s0 = blockIdx.x;

    f4 v[PT], u[PT];
    {
        const f4* p = in + in_base_of(s0) + t;
#pragma unroll
        for (int j = 0; j < PT; ++j)
            v[j] = __builtin_nontemporal_load(p + j * BLOCK);
    }

#pragma unroll
    for (int i = 0; i < NITER; ++i) {
        // ---- prefetch tile i+1 into registers (stays in flight all iter)
        if (i + 1 < NITER) {
            const f4* p = in + in_base_of(s0 + (i + 1) * GRID) + t;
#pragma unroll
            for (int j = 0; j < PT; ++j)
                u[j] = __builtin_nontemporal_load(p + j * BLOCK);
            __builtin_amdgcn_sched_barrier(0);   // pin load issue above barriers
        }

        if (i > 0)
            __builtin_amdgcn_s_barrier();  // WAR: all waves done reading prev tile

        // ---- ds_write v (compiler waits precisely for v's loads, not u's)
#pragma unroll
        for (int j = 0; j < PT; ++j) {
            int idx = t + j * BLOCK;
            int row = idx / ROW4;          // 0..7
            int col = idx - row * ROW4;    // 0..287
            lds[row * LSTR + col] = v[j];
        }
        asm volatile("s_waitcnt lgkmcnt(0)" ::: "memory");
        __builtin_amdgcn_s_barrier();      // tile i visible to all waves

        // ---- gather in output order, coalesced nt stores
        const int ob = out_base_of(s0 + i * GRID);
#pragma unroll
        for (int j = 0; j < PT; ++j) {
            int o  = t + j * BLOCK;        // 0..2303
            int gx = o / 96;               // 0..23
            int w  = o - gx * 96;          // py*12 + k
            int py = w / 12;
            int k  = w - py * 12;
            f4 x = lds[py * LSTR + gx * 12 + k];
            __builtin_nontemporal_store(x, out + ob + gx * 192 + w);
        }

        if (i + 1 < NITER) {
#pragma unroll
            for (int j = 0; j < PT; ++j) v[j] = u[j];
        }
    }
}

extern "C" void kernel_launch(void* const* d_in, const int* in_sizes, int n_in,
                              void* d_out, int out_size, void* d_ws, size_t ws_size,
                              hipStream_t stream) {
    const f4* in  = (const f4*)d_in[0];
    f4*       out = (f4*)d_out;
    patches_kernel<<<GRID, BLOCK, 0, stream>>>(in, out);
}